// Round 11
// baseline (234.427 us; speedup 1.0000x reference)
//
#include <hip/hip_runtime.h>

#define H 128

typedef short short8 __attribute__((ext_vector_type(8)));
typedef float floatx4 __attribute__((ext_vector_type(4)));

__device__ __forceinline__ short f2bf(float f) {
  union { float f; unsigned u; } v; v.f = f;
  unsigned r = v.u + 0x7fffu + ((v.u >> 16) & 1u);  // RNE
  return (short)(r >> 16);
}
__device__ __forceinline__ float bf2f(unsigned u16) {
  union { unsigned u; float f; } v; v.u = u16 << 16;
  return v.f;
}

// Pack W (fp32 [K][N] row-major) into MFMA B-fragment order in LDS:
// slot i = [nt(8)][ks(4)][lane(64)]; v[j] = bf16(W[ks*32+(lane>>4)*8+j][nt*16+(lane&15)])
template <int NTHREADS>
__device__ __forceinline__ void pack_W_lds(const float* __restrict__ W,
                                           short8* bLds, int tid) {
#pragma unroll
  for (int i = tid; i < 2048; i += NTHREADS) {
    const int lane = i & 63, ks = (i >> 6) & 3, nt = i >> 8;
    const int n = nt * 16 + (lane & 15);
    const int k0 = ks * 32 + ((lane >> 4) << 3);
    short8 v;
#pragma unroll
    for (int j = 0; j < 8; j++) v[j] = f2bf(W[(k0 + j) * H + n]);
    bLds[i] = v;
  }
}

// C[64 rows, 128] = relu(A @ W + bias); A fp32 global; C bf16. 4 waves x 16 rows.
__device__ void gemm1_dev(int bid, int tid, const float* __restrict__ A,
                          const float* __restrict__ W1,
                          const float* __restrict__ bias,
                          unsigned short* __restrict__ C, int M,
                          short8* bLds) {
  pack_W_lds<256>(W1, bLds, tid);
  __syncthreads();

  const int wv = tid >> 6, lane = tid & 63;
  const int m0 = bid * 64 + wv * 16;

  floatx4 acc[8];
#pragma unroll
  for (int nt = 0; nt < 8; nt++) acc[nt] = (floatx4)0.f;

  const int arow = lane & 15;
  const int kb = (lane >> 4) << 3;

#pragma unroll
  for (int ks = 0; ks < 4; ks++) {
    short8 af;
    {
      int row = min(m0 + arow, M - 1);  // clamp; garbage rows never stored
      const float* ap = A + (size_t)row * H + (ks << 5) + kb;
      floatx4 x0 = *reinterpret_cast<const floatx4*>(ap);
      floatx4 x1 = *reinterpret_cast<const floatx4*>(ap + 4);
      af[0] = f2bf(x0[0]); af[1] = f2bf(x0[1]);
      af[2] = f2bf(x0[2]); af[3] = f2bf(x0[3]);
      af[4] = f2bf(x1[0]); af[5] = f2bf(x1[1]);
      af[6] = f2bf(x1[2]); af[7] = f2bf(x1[3]);
    }
#pragma unroll
    for (int nt = 0; nt < 8; nt++)
      acc[nt] = __builtin_amdgcn_mfma_f32_16x16x32_bf16(af, bLds[((nt << 2) | ks) * 64 + lane], acc[nt], 0, 0, 0);
  }

  const int crow = (lane >> 4) << 2;
  const int ccol = lane & 15;
#pragma unroll
  for (int nt = 0; nt < 8; nt++) {
    const int col = (nt << 4) + ccol;
    const float bv = bias[col];
#pragma unroll
    for (int r = 0; r < 4; r++) {
      const int row = m0 + crow + r;
      if (row < M) {
        float v = fmaxf(acc[nt][r] + bv, 0.f);
        C[(size_t)row * H + col] = (unsigned short)f2bf(v);
      }
    }
  }
}

// K1: blocks [0, nCnt) count tgt + record rank; blocks [nCnt, ...) do gemm1.
__global__ __launch_bounds__(256) void k1_count_gemm1(
    const int* __restrict__ tgt, int* __restrict__ counts,
    int* __restrict__ rank, int E,
    const float* __restrict__ X, const float* __restrict__ W1,
    const float* __restrict__ b1, unsigned short* __restrict__ Ybf,
    int N, int nCnt) {
  __shared__ short8 bLds[2048];  // 32 KB (gemm blocks only)
  if ((int)blockIdx.x < nCnt) {
    const int e = blockIdx.x * 256 + threadIdx.x;
    if (e < E) rank[e] = atomicAdd(&counts[tgt[e]], 1);
  } else {
    gemm1_dev(blockIdx.x - nCnt, threadIdx.x, X, W1, b1, Ybf, N, bLds);
  }
}

// --- scan: partial sums per 1024-chunk, then final (redundant top scan) ---

__global__ __launch_bounds__(256) void scan_partial(
    const int* __restrict__ counts, int* __restrict__ blockSums, int N) {
  const int tid = threadIdx.x;
  const int base = blockIdx.x * 1024 + tid * 4;
  int4 v = make_int4(0, 0, 0, 0);
  if (base + 3 < N) {
    v = *reinterpret_cast<const int4*>(counts + base);
  } else if (base < N) {
    const int n = N - base;
    v.x = counts[base];
    if (n > 1) v.y = counts[base + 1];
    if (n > 2) v.z = counts[base + 2];
  }
  int s = v.x + v.y + v.z + v.w;
#pragma unroll
  for (int d = 1; d < 64; d <<= 1) s += __shfl_xor(s, d);
  __shared__ int ws[4];
  if ((tid & 63) == 0) ws[tid >> 6] = s;
  __syncthreads();
  if (tid == 0) blockSums[blockIdx.x] = ws[0] + ws[1] + ws[2] + ws[3];
}

// nb <= 64 assumed (N <= 65536): each block redundantly scans blockSums.
__global__ __launch_bounds__(256) void scan_final(
    const int* __restrict__ counts, const int* __restrict__ blockSums,
    int* __restrict__ offsets, int N, int E, int nb) {
  __shared__ int sPrefix;
  const int tid = threadIdx.x, lane = tid & 63, wv = tid >> 6;
  if (tid < 64) {
    const int v = (tid < nb) ? blockSums[tid] : 0;
    int x = v;
#pragma unroll
    for (int d = 1; d < 64; d <<= 1) {
      int t = __shfl_up(x, d);
      if (lane >= d) x += t;
    }
    if (tid == blockIdx.x) sPrefix = x - v;  // exclusive prefix of this block
  }

  const int base = blockIdx.x * 1024 + tid * 4;
  int4 v = make_int4(0, 0, 0, 0);
  if (base + 3 < N) {
    v = *reinterpret_cast<const int4*>(counts + base);
  } else if (base < N) {
    const int n = N - base;
    v.x = counts[base];
    if (n > 1) v.y = counts[base + 1];
    if (n > 2) v.z = counts[base + 2];
  }
  const int s = v.x + v.y + v.z + v.w;
  int x = s;
#pragma unroll
  for (int d = 1; d < 64; d <<= 1) {
    int t = __shfl_up(x, d);
    if (lane >= d) x += t;
  }
  __shared__ int ws[4];
  if (lane == 63) ws[wv] = x;
  __syncthreads();
  int wbase = 0;
  for (int i = 0; i < wv; i++) wbase += ws[i];

  const int excl = sPrefix + wbase + (x - s);
  const int o0 = excl, o1 = o0 + v.x, o2 = o1 + v.y, o3 = o2 + v.z;
  if (base + 3 < N) {
    *reinterpret_cast<int4*>(offsets + base) = make_int4(o0, o1, o2, o3);
  } else if (base < N) {
    const int n = N - base;
    offsets[base] = o0;
    if (n > 1) offsets[base + 1] = o1;
    if (n > 2) offsets[base + 2] = o2;
  }
  if (blockIdx.x == 0 && tid == 0) offsets[N] = E;
}

// atomic-free scatter; pair = src(lo16) | bf16(norm)(hi16)
__global__ __launch_bounds__(256) void fill_edges(
    const int* __restrict__ src, const int* __restrict__ tgt,
    const float* __restrict__ norm, const int* __restrict__ offsets,
    const int* __restrict__ rank, unsigned* __restrict__ pairs, int E) {
  int e = blockIdx.x * blockDim.x + threadIdx.x;
  if (e >= E) return;
  const int pos = offsets[tgt[e]] + rank[e];
  pairs[pos] = (unsigned)(unsigned short)src[e] |
               ((unsigned)(unsigned short)f2bf(norm[e]) << 16);
}

// K5: fused pull + gemm2 + relu + residual. 512 threads = 8 waves, 128 rows.
// Wave wv pulls rows [wv*16, wv*16+16) into LDS A-tile, then gemms them.
__global__ __launch_bounds__(512) void k5_pull_gemm2(
    const unsigned short* __restrict__ Y, const unsigned* __restrict__ pairs,
    const int* __restrict__ offsets, const float* __restrict__ W2,
    const float* __restrict__ b2, const float* __restrict__ X,
    float* __restrict__ out, int N) {
  __shared__ short8 bLds[2048];                 // 32 KB B fragments
  __shared__ unsigned short aLds[128][136];     // 34 KB pooled rows (pad 136)
  const int tid = threadIdx.x, wv = tid >> 6, lane = tid & 63;

  pack_W_lds<512>(W2, bLds, tid);

  // pull phase: wave owns 16 rows
  const int rowBase = blockIdx.x * 128 + wv * 16;
#pragma unroll 1
  for (int r = 0; r < 16; r++) {
    const int node = rowBase + r;
    float ax = 0.f, ay = 0.f;
    if (node < N) {
      int i = offsets[node];
      const int iend = offsets[node + 1];
      for (; i + 7 < iend; i += 8) {
        const uint4 q0 = *reinterpret_cast<const uint4*>(pairs + i);
        const uint4 q1 = *reinterpret_cast<const uint4*>(pairs + i + 4);
        const unsigned p[8] = {q0.x, q0.y, q0.z, q0.w, q1.x, q1.y, q1.z, q1.w};
        unsigned v[8];
#pragma unroll
        for (int j = 0; j < 8; j++)
          v[j] = *reinterpret_cast<const unsigned*>(
              Y + (size_t)(p[j] & 0xffffu) * H + lane * 2);
#pragma unroll
        for (int j = 0; j < 8; j++) {
          const float n = bf2f(p[j] >> 16);
          ax = fmaf(n, bf2f(v[j] & 0xffffu), ax);
          ay = fmaf(n, bf2f(v[j] >> 16), ay);
        }
      }
      for (; i < iend; i++) {
        const unsigned p = pairs[i];
        const unsigned v = *reinterpret_cast<const unsigned*>(
            Y + (size_t)(p & 0xffffu) * H + lane * 2);
        const float n = bf2f(p >> 16);
        ax = fmaf(n, bf2f(v & 0xffffu), ax);
        ay = fmaf(n, bf2f(v >> 16), ay);
      }
    }
    *reinterpret_cast<unsigned*>(&aLds[wv * 16 + r][lane * 2]) =
        ((unsigned)(unsigned short)f2bf(ay) << 16) | (unsigned short)f2bf(ax);
  }
  __syncthreads();

  // gemm phase: wave wv computes its 16 rows x 128 cols
  floatx4 acc[8];
#pragma unroll
  for (int nt = 0; nt < 8; nt++) acc[nt] = (floatx4)0.f;

  const int arow = lane & 15;
  const int kb = (lane >> 4) << 3;

#pragma unroll
  for (int ks = 0; ks < 4; ks++) {
    const short8 af = *reinterpret_cast<const short8*>(
        &aLds[wv * 16 + arow][(ks << 5) + kb]);
#pragma unroll
    for (int nt = 0; nt < 8; nt++)
      acc[nt] = __builtin_amdgcn_mfma_f32_16x16x32_bf16(af, bLds[((nt << 2) | ks) * 64 + lane], acc[nt], 0, 0, 0);
  }

  const int crow = (lane >> 4) << 2;
  const int ccol = lane & 15;
#pragma unroll
  for (int nt = 0; nt < 8; nt++) {
    const int col = (nt << 4) + ccol;
    const float bv = b2[col];
#pragma unroll
    for (int r = 0; r < 4; r++) {
      const int row = rowBase + crow + r;
      if (row < N) {
        const float v = fmaxf(acc[nt][r] + bv, 0.f);
        out[(size_t)row * H + col] = v + X[(size_t)row * H + col];
      }
    }
  }
}

extern "C" void kernel_launch(void* const* d_in, const int* in_sizes, int n_in,
                              void* d_out, int out_size, void* d_ws, size_t ws_size,
                              hipStream_t stream) {
  const float* X    = (const float*)d_in[0];
  const int*   src  = (const int*)d_in[1];
  const int*   tgt  = (const int*)d_in[2];
  const float* norm = (const float*)d_in[3];
  const float* W1   = (const float*)d_in[4];
  const float* b1   = (const float*)d_in[5];
  const float* W2   = (const float*)d_in[6];
  const float* b2   = (const float*)d_in[7];
  float* out = (float*)d_out;

  const int N = in_sizes[0] / H;   // 50000
  const int E = in_sizes[1];       // 800000

  // workspace carve (256B-aligned) — ~20 MB
  auto align_up = [](size_t x) { return (x + 255) & ~(size_t)255; };
  char* w = (char*)d_ws;
  unsigned short* Ybf   = (unsigned short*)w; w += align_up((size_t)N * H * 2);
  int*   counts   = (int*)w;   w += align_up((size_t)N * sizeof(int));
  int*   offsets  = (int*)w;   w += align_up((size_t)(N + 1) * sizeof(int));
  int*   rank     = (int*)w;   w += align_up((size_t)E * sizeof(int));
  int*   blockSums= (int*)w;   w += align_up((size_t)1024 * sizeof(int));
  unsigned* pairs = (unsigned*)w; w += align_up((size_t)E * sizeof(unsigned));

  hipMemsetAsync(counts, 0, (size_t)N * sizeof(int), stream);

  const int eb = (E + 255) / 256;          // 3125 count blocks
  const int gemm_blocks = (N + 63) / 64;   // 782 gemm1 blocks
  k1_count_gemm1<<<eb + gemm_blocks, 256, 0, stream>>>(
      tgt, counts, rank, E, X, W1, b1, Ybf, N, eb);

  const int nb = (N + 1023) / 1024;  // 49 (<= 64 required)
  scan_partial<<<nb, 256, 0, stream>>>(counts, blockSums, N);
  scan_final<<<nb, 256, 0, stream>>>(counts, blockSums, offsets, N, E, nb);

  fill_edges<<<eb, 256, 0, stream>>>(src, tgt, norm, offsets, rank, pairs, E);

  k5_pull_gemm2<<<(N + 127) / 128, 512, 0, stream>>>(
      Ybf, pairs, offsets, W2, b2, X, out, N);
}

// Round 12
// 199.605 us; speedup vs baseline: 1.1745x; 1.1745x over previous
//
#include <hip/hip_runtime.h>

#define H 128

typedef short short8 __attribute__((ext_vector_type(8)));
typedef float floatx4 __attribute__((ext_vector_type(4)));

__device__ __forceinline__ short f2bf(float f) {
  union { float f; unsigned u; } v; v.f = f;
  unsigned r = v.u + 0x7fffu + ((v.u >> 16) & 1u);  // RNE
  return (short)(r >> 16);
}
__device__ __forceinline__ float bf2f(unsigned u16) {
  union { unsigned u; float f; } v; v.u = u16 << 16;
  return v.f;
}

// K0: pack W1/W2 (fp32 [K][N]) into MFMA B-fragment order (16 blocks).
// Bp[((nt*4+ks)*64+lane)*8 + j] = bf16(W[ks*32+(lane>>4)*8+j][nt*16+(lane&15)])
__global__ __launch_bounds__(256) void pack_W(
    const float* __restrict__ W1, const float* __restrict__ W2,
    short* __restrict__ Bp1, short* __restrict__ Bp2) {
  const int t = blockIdx.x * 256 + threadIdx.x;  // 0..4095
  const float* W = (t >> 11) ? W2 : W1;
  short* Bp = (t >> 11) ? Bp2 : Bp1;
  const int i = t & 2047;  // [nt(8)][ks(4)][lane(64)]
  const int lane = i & 63, ks = (i >> 6) & 3, nt = i >> 8;
  const int n = nt * 16 + (lane & 15);
  const int k0 = ks * 32 + ((lane >> 4) << 3);
  short8 v;
#pragma unroll
  for (int j = 0; j < 8; j++) v[j] = f2bf(W[(k0 + j) * H + n]);
  *reinterpret_cast<short8*>(Bp + (size_t)i * 8) = v;
}

// gemm body: C[64 rows,128] = relu(A@W+bias)(+R); B pre-packed, staged to LDS.
// 256 threads = 4 waves, wave owns 16 rows. A fp32 or bf16; C fp32 or bf16.
template <bool A_BF16, bool C_BF16, bool RESID>
__device__ __forceinline__ void gemm_dev(
    int bid, int tid, const void* __restrict__ Av, const short* __restrict__ Bp,
    const float* __restrict__ bias, const float* __restrict__ R,
    void* __restrict__ Cv, int M, int4* bLds) {
  {
    const int4* g = reinterpret_cast<const int4*>(Bp);
#pragma unroll
    for (int i = 0; i < 8; i++) bLds[tid + i * 256] = g[tid + i * 256];
  }
  __syncthreads();

  const int wv = tid >> 6, lane = tid & 63;
  const int m0 = bid * 64 + wv * 16;

  floatx4 acc[8];
#pragma unroll
  for (int nt = 0; nt < 8; nt++) acc[nt] = (floatx4)0.f;

  const int arow = lane & 15;
  const int kb = (lane >> 4) << 3;
  const short8* bL = reinterpret_cast<const short8*>(bLds);

#pragma unroll
  for (int ks = 0; ks < 4; ks++) {
    short8 af;
    {
      int row = min(m0 + arow, M - 1);  // clamp; garbage rows never stored
      const size_t off = (size_t)row * H + (ks << 5) + kb;
      if (A_BF16) {
        af = *reinterpret_cast<const short8*>((const short*)Av + off);
      } else {
        const float* ap = (const float*)Av + off;
        floatx4 x0 = *reinterpret_cast<const floatx4*>(ap);
        floatx4 x1 = *reinterpret_cast<const floatx4*>(ap + 4);
        af[0] = f2bf(x0[0]); af[1] = f2bf(x0[1]);
        af[2] = f2bf(x0[2]); af[3] = f2bf(x0[3]);
        af[4] = f2bf(x1[0]); af[5] = f2bf(x1[1]);
        af[6] = f2bf(x1[2]); af[7] = f2bf(x1[3]);
      }
    }
#pragma unroll
    for (int nt = 0; nt < 8; nt++)
      acc[nt] = __builtin_amdgcn_mfma_f32_16x16x32_bf16(
          af, bL[((nt << 2) | ks) * 64 + lane], acc[nt], 0, 0, 0);
  }

  const int crow = (lane >> 4) << 2;
  const int ccol = lane & 15;
#pragma unroll
  for (int nt = 0; nt < 8; nt++) {
    const int col = (nt << 4) + ccol;
    const float bv = bias[col];
#pragma unroll
    for (int r = 0; r < 4; r++) {
      const int row = m0 + crow + r;
      if (row < M) {
        float v = fmaxf(acc[nt][r] + bv, 0.f);
        if (RESID) v += R[(size_t)row * H + col];
        if (C_BF16)
          ((short*)Cv)[(size_t)row * H + col] = f2bf(v);
        else
          ((float*)Cv)[(size_t)row * H + col] = v;
      }
    }
  }
}

// K1: blocks [0,nCnt) count tgt + record rank; blocks [nCnt,..) do gemm1.
__global__ __launch_bounds__(256) void k1_count_gemm1(
    const int* __restrict__ tgt, int* __restrict__ counts,
    int* __restrict__ rank, int E,
    const float* __restrict__ X, const short* __restrict__ Bp1,
    const float* __restrict__ b1, unsigned short* __restrict__ Ybf,
    int N, int nCnt) {
  __shared__ int4 bLds[2048];  // 32 KB (gemm blocks only)
  if ((int)blockIdx.x < nCnt) {
    const int e = blockIdx.x * 256 + threadIdx.x;
    if (e < E) rank[e] = atomicAdd(&counts[tgt[e]], 1);
  } else {
    gemm_dev<false, true, false>(blockIdx.x - nCnt, threadIdx.x, X, Bp1, b1,
                                 nullptr, Ybf, N, bLds);
  }
}

__global__ __launch_bounds__(256) void gemm2_kernel(
    const unsigned short* __restrict__ pool, const short* __restrict__ Bp2,
    const float* __restrict__ b2, const float* __restrict__ X,
    float* __restrict__ out, int N) {
  __shared__ int4 bLds[2048];
  gemm_dev<true, false, true>(blockIdx.x, threadIdx.x, pool, Bp2, b2, X, out,
                              N, bLds);
}

// --- scan: partial sums per 1024-chunk, then final (redundant top scan) ---

__global__ __launch_bounds__(256) void scan_partial(
    const int* __restrict__ counts, int* __restrict__ blockSums, int N) {
  const int tid = threadIdx.x;
  const int base = blockIdx.x * 1024 + tid * 4;
  int4 v = make_int4(0, 0, 0, 0);
  if (base + 3 < N) {
    v = *reinterpret_cast<const int4*>(counts + base);
  } else if (base < N) {
    const int n = N - base;
    v.x = counts[base];
    if (n > 1) v.y = counts[base + 1];
    if (n > 2) v.z = counts[base + 2];
  }
  int s = v.x + v.y + v.z + v.w;
#pragma unroll
  for (int d = 1; d < 64; d <<= 1) s += __shfl_xor(s, d);
  __shared__ int ws[4];
  if ((tid & 63) == 0) ws[tid >> 6] = s;
  __syncthreads();
  if (tid == 0) blockSums[blockIdx.x] = ws[0] + ws[1] + ws[2] + ws[3];
}

// nb <= 64 assumed (N <= 65536): each block redundantly scans blockSums.
__global__ __launch_bounds__(256) void scan_final(
    const int* __restrict__ counts, const int* __restrict__ blockSums,
    int* __restrict__ offsets, int N, int E, int nb) {
  __shared__ int sPrefix;
  const int tid = threadIdx.x, lane = tid & 63, wv = tid >> 6;
  if (tid < 64) {
    const int v = (tid < nb) ? blockSums[tid] : 0;
    int x = v;
#pragma unroll
    for (int d = 1; d < 64; d <<= 1) {
      int t = __shfl_up(x, d);
      if (lane >= d) x += t;
    }
    if (tid == blockIdx.x) sPrefix = x - v;  // exclusive prefix of this block
  }

  const int base = blockIdx.x * 1024 + tid * 4;
  int4 v = make_int4(0, 0, 0, 0);
  if (base + 3 < N) {
    v = *reinterpret_cast<const int4*>(counts + base);
  } else if (base < N) {
    const int n = N - base;
    v.x = counts[base];
    if (n > 1) v.y = counts[base + 1];
    if (n > 2) v.z = counts[base + 2];
  }
  const int s = v.x + v.y + v.z + v.w;
  int x = s;
#pragma unroll
  for (int d = 1; d < 64; d <<= 1) {
    int t = __shfl_up(x, d);
    if (lane >= d) x += t;
  }
  __shared__ int ws[4];
  if (lane == 63) ws[wv] = x;
  __syncthreads();
  int wbase = 0;
  for (int i = 0; i < wv; i++) wbase += ws[i];

  const int excl = sPrefix + wbase + (x - s);
  const int o0 = excl, o1 = o0 + v.x, o2 = o1 + v.y, o3 = o2 + v.z;
  if (base + 3 < N) {
    *reinterpret_cast<int4*>(offsets + base) = make_int4(o0, o1, o2, o3);
  } else if (base < N) {
    const int n = N - base;
    offsets[base] = o0;
    if (n > 1) offsets[base + 1] = o1;
    if (n > 2) offsets[base + 2] = o2;
  }
  if (blockIdx.x == 0 && tid == 0) offsets[N] = E;
}

// atomic-free scatter; pair = src(lo16) | bf16(norm)(hi16)
__global__ __launch_bounds__(256) void fill_edges(
    const int* __restrict__ src, const int* __restrict__ tgt,
    const float* __restrict__ norm, const int* __restrict__ offsets,
    const int* __restrict__ rank, unsigned* __restrict__ pairs, int E) {
  int e = blockIdx.x * blockDim.x + threadIdx.x;
  if (e >= E) return;
  const int pos = offsets[tgt[e]] + rank[e];
  pairs[pos] = (unsigned)(unsigned short)src[e] |
               ((unsigned)(unsigned short)f2bf(norm[e]) << 16);
}

// one wave per node: gather bf16 Y rows, fp32 accumulate, bf16 store.
// ILP x8 main loop + ONE predicated 8-wide tail (zero-norm padding).
__global__ __launch_bounds__(256) void pull_pool(
    const unsigned short* __restrict__ Y, const unsigned* __restrict__ pairs,
    const int* __restrict__ offsets, unsigned* __restrict__ pooled, int N) {
  const int node = blockIdx.x * 4 + (threadIdx.x >> 6);
  if (node >= N) return;
  const int lane = threadIdx.x & 63;
  int i = offsets[node];
  const int iend = offsets[node + 1];

  float ax = 0.f, ay = 0.f;
  for (; i + 7 < iend; i += 8) {
    const uint4 q0 = *reinterpret_cast<const uint4*>(pairs + i);
    const uint4 q1 = *reinterpret_cast<const uint4*>(pairs + i + 4);
    const unsigned p[8] = {q0.x, q0.y, q0.z, q0.w, q1.x, q1.y, q1.z, q1.w};
    unsigned v[8];
#pragma unroll
    for (int j = 0; j < 8; j++)
      v[j] = *reinterpret_cast<const unsigned*>(
          Y + (size_t)(p[j] & 0xffffu) * H + lane * 2);
#pragma unroll
    for (int j = 0; j < 8; j++) {
      const float n = bf2f(p[j] >> 16);
      ax = fmaf(n, bf2f(v[j] & 0xffffu), ax);
      ay = fmaf(n, bf2f(v[j] >> 16), ay);
    }
  }
  if (i < iend) {
    unsigned p[8];
#pragma unroll
    for (int j = 0; j < 8; j++) p[j] = (i + j < iend) ? pairs[i + j] : 0u;
    unsigned v[8];
#pragma unroll
    for (int j = 0; j < 8; j++)
      v[j] = *reinterpret_cast<const unsigned*>(
          Y + (size_t)(p[j] & 0xffffu) * H + lane * 2);
#pragma unroll
    for (int j = 0; j < 8; j++) {
      const float n = bf2f(p[j] >> 16);  // 0 for padded slots
      ax = fmaf(n, bf2f(v[j] & 0xffffu), ax);
      ay = fmaf(n, bf2f(v[j] >> 16), ay);
    }
  }
  pooled[(size_t)node * 64 + lane] =
      ((unsigned)(unsigned short)f2bf(ay) << 16) | (unsigned short)f2bf(ax);
}

extern "C" void kernel_launch(void* const* d_in, const int* in_sizes, int n_in,
                              void* d_out, int out_size, void* d_ws, size_t ws_size,
                              hipStream_t stream) {
  const float* X    = (const float*)d_in[0];
  const int*   src  = (const int*)d_in[1];
  const int*   tgt  = (const int*)d_in[2];
  const float* norm = (const float*)d_in[3];
  const float* W1   = (const float*)d_in[4];
  const float* b1   = (const float*)d_in[5];
  const float* W2   = (const float*)d_in[6];
  const float* b2   = (const float*)d_in[7];
  float* out = (float*)d_out;

  const int N = in_sizes[0] / H;   // 50000
  const int E = in_sizes[1];       // 800000

  // workspace carve (256B-aligned) — ~33 MB
  auto align_up = [](size_t x) { return (x + 255) & ~(size_t)255; };
  char* w = (char*)d_ws;
  unsigned short* Ybf   = (unsigned short*)w; w += align_up((size_t)N * H * 2);
  unsigned short* pool  = (unsigned short*)w; w += align_up((size_t)N * H * 2);
  int*   counts   = (int*)w;   w += align_up((size_t)N * sizeof(int));
  int*   offsets  = (int*)w;   w += align_up((size_t)(N + 1) * sizeof(int));
  int*   rank     = (int*)w;   w += align_up((size_t)E * sizeof(int));
  int*   blockSums= (int*)w;   w += align_up((size_t)1024 * sizeof(int));
  short* Bp1      = (short*)w; w += align_up((size_t)16384 * sizeof(short));
  short* Bp2      = (short*)w; w += align_up((size_t)16384 * sizeof(short));
  unsigned* pairs = (unsigned*)w; w += align_up((size_t)E * sizeof(unsigned));

  hipMemsetAsync(counts, 0, (size_t)N * sizeof(int), stream);

  pack_W<<<16, 256, 0, stream>>>(W1, W2, Bp1, Bp2);

  const int eb = (E + 255) / 256;          // 3125 count blocks
  const int gemm_blocks = (N + 63) / 64;   // 782 gemm blocks
  k1_count_gemm1<<<eb + gemm_blocks, 256, 0, stream>>>(
      tgt, counts, rank, E, X, Bp1, b1, Ybf, N, eb);

  const int nb = (N + 1023) / 1024;  // 49 (<= 64 required)
  scan_partial<<<nb, 256, 0, stream>>>(counts, blockSums, N);
  scan_final<<<nb, 256, 0, stream>>>(counts, blockSums, offsets, N, E, nb);

  fill_edges<<<eb, 256, 0, stream>>>(src, tgt, norm, offsets, rank, pairs, E);

  pull_pool<<<(N + 3) / 4, 256, 0, stream>>>(
      Ybf, pairs, offsets, (unsigned*)pool, N);

  gemm2_kernel<<<gemm_blocks, 256, 0, stream>>>(pool, Bp2, b2, X, out, N);
}